// Round 1
// 9833.083 us; speedup vs baseline: 1.2197x; 1.2197x over previous
//
#include <hip/hip_runtime.h>
#include <cstdint>
#include <cstddef>

// B=256, P=196, C=512, D=512, A=256, E=256, V=193, TC=256, T=255

typedef unsigned short u16;
typedef unsigned int u32;
typedef __attribute__((ext_vector_type(8))) short short8;
typedef __attribute__((ext_vector_type(4))) float f32x4;

__device__ __forceinline__ float sigf(float x){ return 1.f/(1.f+expf(-x)); }
__device__ __forceinline__ u16 f2bf(float f){
  u32 u = __builtin_bit_cast(u32, f);
  u32 r = (u + 0x7fffu + ((u>>16)&1u)) >> 16;
  return (u16)r;
}
__device__ __forceinline__ float bf2f(u16 u){
  u32 x = ((u32)u) << 16;
  return __builtin_bit_cast(float, x);
}

// ---------------- zero preds/alphas (harness poisons d_out every launch) ----------------
__global__ void k_zero(float* a, int na4, float* b, int nb4){
  int i = blockIdx.x*blockDim.x + threadIdx.x;
  int stride = gridDim.x*blockDim.x;
  float4 z = make_float4(0.f,0.f,0.f,0.f);
  for (int j = i; j < na4; j += stride) ((float4*)a)[j] = z;
  for (int j = i; j < nb4; j += stride) ((float4*)b)[j] = z;
}

// ---------------- sort (stable descending by length) ----------------
__global__ void k_sort(const int* cap_lens, int* si, int* dlw, float* out_dl, float* out_si){
  __shared__ int lens[256];
  int tid = threadIdx.x;
  lens[tid] = cap_lens[tid];
  __syncthreads();
  int L = lens[tid];
  int rank = 0;
  for (int j = 0; j < 256; ++j){
    int Lj = lens[j];
    rank += ((Lj > L) || (Lj == L && j < tid)) ? 1 : 0;
  }
  si[rank] = tid;
  dlw[rank] = L - 1;
  out_dl[rank] = (float)(L - 1);
  out_si[rank] = (float)tid;
}

// ---------------- caps gather ----------------
__global__ void k_caps(const int* caps, const int* si, int* caps_s, float* out_caps){
  int b = blockIdx.x, t = threadIdx.x;
  int v = caps[si[b]*256 + t];
  caps_s[b*256 + t] = v;
  out_caps[b*256 + t] = (float)v;
}

// ---------------- gather+convert encoder rows to bf16 (sorted order) ----------------
__global__ void k_prep(const float* enc, const int* si, u16* enc_sb){
  int b = blockIdx.x, tid = threadIdx.x;
  const float* src = enc + (size_t)si[b]*100352;   // 196*512
  u16* dst = enc_sb + (size_t)b*100352;
  for (int i = tid; i < 25088; i += 256){
    float4 v = *(const float4*)&src[i*4];
    ushort4 o;
    o.x = f2bf(v.x); o.y = f2bf(v.y); o.z = f2bf(v.z); o.w = f2bf(v.w);
    *(ushort4*)&dst[i*4] = o;
  }
}

// ---------------- mean of encoder rows (sorted order), bf16 out ----------------
__global__ void k_mean(const float* enc, const int* si, u16* mean_bf){
  int b = blockIdx.x, tid = threadIdx.x;
  const float* eb = enc + (size_t)si[b]*100352;
  int cc = 2*tid;
  float s0 = 0.f, s1 = 0.f;
  #pragma unroll 4
  for (int pp = 0; pp < 196; ++pp){
    float2 v = *(const float2*)&eb[(size_t)pp*512 + cc];
    s0 += v.x; s1 += v.y;
  }
  mean_bf[b*512 + cc]     = f2bf(s0 * (1.f/196.f));
  mean_bf[b*512 + cc + 1] = f2bf(s1 * (1.f/196.f));
}

// ---------------- weight concat + bf16 convert ----------------
struct ConcatP {
  const float *Wdec,*bdec,*Wfb,*bfb,*Wfc,*bfc,*Wih,*bih,*Whh,*bhh,*Winh,*binh,*Winc,*binc,*Wenc,*emb;
  u16 *Wc0,*Wc1,*Wc3,*Wenc_bf,*emb_bf;
  float *bc0,*bc1,*bc3;
};
__global__ void k_concat(ConcatP p){
  int idx = blockIdx.x*blockDim.x + threadIdx.x;
  int stride = gridDim.x*blockDim.x;
  for (int i = idx; i < 1024*512; i += stride){
    int n = i >> 9, k = i & 511;
    float v = (n < 512) ? p.Winh[n*512 + k] : p.Winc[(n-512)*512 + k];
    p.Wc0[i] = f2bf(v);
  }
  for (int i = idx; i < 1024; i += stride)
    p.bc0[i] = (i < 512) ? p.binh[i] : p.binc[i-512];
  for (int i = idx; i < 1024*512; i += stride){
    int n = i >> 9, k = i & 511;
    float v = (n < 256) ? p.Wdec[n*512+k]
            : (n < 768) ? p.Wfb[(n-256)*512+k]
            : (n < 961) ? p.Wfc[(n-768)*512+k] : 0.f;
    p.Wc1[i] = f2bf(v);
  }
  for (int i = idx; i < 1024; i += stride)
    p.bc1[i] = (i < 256) ? p.bdec[i] : (i < 768) ? p.bfb[i-256] : (i < 961) ? p.bfc[i-768] : 0.f;
  // Wc3: gate-interleaved [W_ih | W_hh] (2048 x 1280), row n'=4*j+g -> orig row g*512+j
  for (int i = idx; i < 2048*1280; i += stride){
    int n = i / 1280, k = i - n*1280;
    int j = n >> 2, g = n & 3, orow = g*512 + j;
    float v = (k < 768) ? p.Wih[orow*768 + k] : p.Whh[orow*512 + (k - 768)];
    p.Wc3[i] = f2bf(v);
  }
  for (int i = idx; i < 2048; i += stride){
    int j = i >> 2, g = i & 3, orow = g*512 + j;
    p.bc3[i] = p.bih[orow] + p.bhh[orow];
  }
  for (int i = idx; i < 256*512; i += stride) p.Wenc_bf[i] = f2bf(p.Wenc[i]);
  for (int i = idx; i < 193*256; i += stride) p.emb_bf[i] = f2bf(p.emb[i]);
}

// ---------------- bf16 MFMA GEMM, double-buffered: C(MxN) = A(MxK)*B(NxK)^T ----------------
// tile 64(M) x 64*NT(N), BK=64; 4 waves, each 4 m-tiles x NT n-tiles of 16x16x32
// MODE 0: enc_att -> bf16 (+bias);  MODE 1: init h/c;  MODE 2: K1 (skip if dl[bm0] < t)
// MODE 3: K3 fused LSTM (skip if dl[bm0] <= t)
struct MfmaP {
  const u16* A; const u16* Bw; const float* bias;
  int K, N;
  u16* out_bf;
  u16* h_bf; float* c;
  float* dec_att; float* gatev; float* preds; const int* dl; int t;
};

template<int MODE, int NT>
__global__ __launch_bounds__(256) void k_mfma(MfmaP p){
  __shared__ __align__(16) unsigned char smem[16384 + 16384*NT];
  u16* As0 = (u16*)smem;                 // [2][64*64]
  u16* Bs0 = (u16*)(smem + 16384);       // [2][64*64*NT]
  float* Cs = (float*)smem;              // MODE 3 epilogue overlay: 64 x 68 f32

  const int tid  = threadIdx.x;
  const int bn0  = blockIdx.x * 64 * NT;
  const int bm0  = blockIdx.y * 64;
  const int wave = tid >> 6;
  const int lane = tid & 63;
  const int ln   = lane & 15;
  const int quad = lane >> 4;

  if (MODE == 2){ if (p.dl[bm0] <  p.t) return; }
  if (MODE == 3){ if (p.dl[bm0] <= p.t) return; }

  f32x4 acc[4][NT] = {};
  short8 pa[2], pb[2*NT];

  const int srow = tid >> 3;          // 0..31
  const int sgc  = tid & 7;           // granule col 0..7

  // prefetch k0=0
  #pragma unroll
  for (int r = 0; r < 2; ++r)
    pa[r] = *(const short8*)(p.A + (size_t)(bm0 + srow + 32*r)*p.K + sgc*8);
  #pragma unroll
  for (int r = 0; r < 2*NT; ++r)
    pb[r] = *(const short8*)(p.Bw + (size_t)(bn0 + srow + 32*r)*p.K + sgc*8);
  // store buf 0
  #pragma unroll
  for (int r = 0; r < 2; ++r){
    int row = srow + 32*r;
    *(short8*)&As0[row*64 + ((sgc ^ (row & 7))<<3)] = pa[r];
  }
  #pragma unroll
  for (int r = 0; r < 2*NT; ++r){
    int row = srow + 32*r;
    *(short8*)&Bs0[row*64 + ((sgc ^ (row & 7))<<3)] = pb[r];
  }

  const int nIter = p.K >> 6;
  int ib = 0;
  for (int it = 0; ; ){
    __syncthreads();
    const bool more = (it + 1 < nIter);
    if (more){
      int k0 = (it + 1) << 6;
      #pragma unroll
      for (int r = 0; r < 2; ++r)
        pa[r] = *(const short8*)(p.A + (size_t)(bm0 + srow + 32*r)*p.K + k0 + sgc*8);
      #pragma unroll
      for (int r = 0; r < 2*NT; ++r)
        pb[r] = *(const short8*)(p.Bw + (size_t)(bn0 + srow + 32*r)*p.K + k0 + sgc*8);
    }
    const u16* As = &As0[ib*4096];
    const u16* Bs = &Bs0[ib*4096*NT];
    #pragma unroll
    for (int kk = 0; kk < 2; ++kk){
      short8 af[4], bfr[NT];
      #pragma unroll
      for (int mt = 0; mt < 4; ++mt){
        int row = mt*16 + ln;
        int g = kk*4 + quad;
        af[mt] = *(const short8*)&As[row*64 + ((g ^ (row & 7))<<3)];
      }
      #pragma unroll
      for (int nt = 0; nt < NT; ++nt){
        int row = (wave*NT + nt)*16 + ln;
        int g = kk*4 + quad;
        bfr[nt] = *(const short8*)&Bs[row*64 + ((g ^ (row & 7))<<3)];
      }
      #pragma unroll
      for (int mt = 0; mt < 4; ++mt)
        #pragma unroll
        for (int nt = 0; nt < NT; ++nt)
          acc[mt][nt] = __builtin_amdgcn_mfma_f32_16x16x32_bf16(af[mt], bfr[nt], acc[mt][nt], 0, 0, 0);
    }
    if (!more) break;
    ib ^= 1;
    u16* Aw = &As0[ib*4096];
    u16* Bww = &Bs0[ib*4096*NT];
    #pragma unroll
    for (int r = 0; r < 2; ++r){
      int row = srow + 32*r;
      *(short8*)&Aw[row*64 + ((sgc ^ (row & 7))<<3)] = pa[r];
    }
    #pragma unroll
    for (int r = 0; r < 2*NT; ++r){
      int row = srow + 32*r;
      *(short8*)&Bww[row*64 + ((sgc ^ (row & 7))<<3)] = pb[r];
    }
    ++it;
  }

  if (MODE == 3){
    // gates tile -> LDS (+bias), regroup (i,f,g,o) quads, fused LSTM pointwise
    __syncthreads();
    {
      int n_loc = wave*16 + ln;     // NT==1
      float bv = p.bias[bn0 + n_loc];
      #pragma unroll
      for (int mt = 0; mt < 4; ++mt)
        #pragma unroll
        for (int r = 0; r < 4; ++r)
          Cs[(mt*16 + quad*4 + r)*68 + n_loc] = acc[mt][0][r] + bv;
    }
    __syncthreads();
    #pragma unroll
    for (int r = 0; r < 4; ++r){
      int idx = r*256 + tid;          // 64 rows x 16 unit-quads
      int m = idx >> 4, jl = idx & 15;
      float4 g4 = *(const float4*)&Cs[m*68 + jl*4];
      int gm = bm0 + m;
      int gj = (bn0 >> 2) + jl;
      if (p.t < p.dl[gm]){
        float ig = sigf(g4.x), fg = sigf(g4.y);
        float gg = tanhf(g4.z), og = sigf(g4.w);
        float cn = fg * p.c[gm*512 + gj] + ig * gg;
        float hn = og * tanhf(cn);
        p.c[gm*512 + gj] = cn;
        p.h_bf[gm*512 + gj] = f2bf(hn);
      }
    }
  } else {
    #pragma unroll
    for (int nt = 0; nt < NT; ++nt){
      int n = bn0 + (wave*NT + nt)*16 + ln;
      float bv = p.bias[n];
      #pragma unroll
      for (int mt = 0; mt < 4; ++mt)
        #pragma unroll
        for (int r = 0; r < 4; ++r){
          int m = bm0 + mt*16 + quad*4 + r;
          float v = acc[mt][nt][r] + bv;
          if (MODE == 0){
            p.out_bf[(size_t)m*p.N + n] = f2bf(v);
          } else if (MODE == 1){
            if (n < 512) p.h_bf[m*512 + n] = f2bf(v);
            else         p.c[m*512 + n - 512] = v;
          } else { // MODE 2
            if (n < 256)      p.dec_att[m*256 + n] = v;
            else if (n < 768) p.gatev[m*512 + n - 256] = sigf(v);
            else if (n < 961){
              int tp = p.t - 1;
              if (tp >= 0)
                p.preds[((size_t)m*255 + tp)*193 + (n - 768)] = (tp < p.dl[m]) ? v : 0.f;
            }
          }
        }
    }
  }
}

// ---------------- attention per batch element (bf16 streams) ----------------
// 1024 threads (16 waves): scores split 4-way over A-dim, awe split 4-way over P.
struct AttnP {
  const u16* enc_att_bf; const u16* enc_sb;
  const float* dec_att; const float* gatev;
  const float* wfull; const float* bfull;
  const u16* emb_bf; const int* caps_s;
  const u16* h_bf; u16* z_bf; float* alphas; const int* dl; int t;
};
__global__ __launch_bounds__(1024) void k_attn(AttnP p){
  __shared__ __align__(16) float da[256];
  __shared__ __align__(16) float wfs[256];
  __shared__ __align__(16) float sc[256];       // scores -> alpha
  __shared__ __align__(16) float awe_r[4][512]; // per-quarter awe partials
  __shared__ float red[20];                     // [0..15] wave partials, [16] combined
  const int b = blockIdx.x, tid = threadIdx.x;
  if (p.t >= p.dl[b]) return;      // inactive: alphas pre-zeroed, h/c/z untouched
  if (tid < 256){
    da[tid]  = p.dec_att[b*256 + tid];
    wfs[tid] = p.wfull[tid];
  }
  __syncthreads();

  // ---- scores: thread (pr, aq) computes partial over 64 A-entries ----
  {
    const int pr = tid >> 2, aq = tid & 3;
    float s = 0.f;
    if (pr < 196){
      const u16* row = p.enc_att_bf + ((size_t)b*196 + pr)*256 + aq*64;
      const float* dd = &da[aq*64];
      const float* ww = &wfs[aq*64];
      #pragma unroll
      for (int i = 0; i < 8; ++i){
        short8 v = *(const short8*)(row + i*8);
        #pragma unroll
        for (int j = 0; j < 8; ++j)
          s += fmaxf(bf2f((u16)v[j]) + dd[i*8+j], 0.f) * ww[i*8+j];
      }
    }
    // quad reduce (lanes 4p..4p+3 share pr)
    s += __shfl_xor(s, 1, 64);
    s += __shfl_xor(s, 2, 64);
    if ((tid & 3) == 0 && pr < 196) sc[pr] = s + p.bfull[0];
  }
  __syncthreads();

  // ---- softmax over 196 (all waves run the shfl; only waves 0-3 hold data) ----
  const int wid = tid >> 6, lane = tid & 63;
  float sv = (tid < 196) ? sc[tid] : -1e30f;
  float mx = sv;
  for (int o = 32; o > 0; o >>= 1) mx = fmaxf(mx, __shfl_down(mx, o, 64));
  if (lane == 0) red[wid] = mx;
  __syncthreads();
  if (tid == 0) red[16] = fmaxf(fmaxf(red[0], red[1]), fmaxf(red[2], red[3]));
  __syncthreads();
  mx = red[16];
  float e = (tid < 196) ? expf(sv - mx) : 0.f;
  float sm = e;
  for (int o = 32; o > 0; o >>= 1) sm += __shfl_down(sm, o, 64);
  if (lane == 0) red[wid] = sm;
  __syncthreads();
  if (tid == 0) red[16] = red[0] + red[1] + red[2] + red[3];
  __syncthreads();
  const float inv = 1.f / red[16];
  if (tid < 256) sc[tid] = e * inv;
  __syncthreads();
  if (tid < 196)
    p.alphas[((size_t)b*255 + p.t)*196 + tid] = sc[tid];

  // ---- awe: thread (q, cp): quarter q of P, channel pair cc ----
  {
    const int q = tid >> 8, cp = tid & 255, cc = 2*cp;
    const u16* eb = p.enc_sb + (size_t)b*100352;
    const int p0 = q*49;
    float v0 = 0.f, v1 = 0.f;
    #pragma unroll 7
    for (int i = 0; i < 49; ++i){
      int pp = p0 + i;
      u32 u = *(const u32*)&eb[(size_t)pp*512 + cc];
      float a = sc[pp];
      v0 += a * bf2f((u16)(u & 0xffffu));
      v1 += a * bf2f((u16)(u >> 16));
    }
    *(float2*)&awe_r[q][cc] = make_float2(v0, v1);
  }
  __syncthreads();

  // ---- combine + z assembly (first 256 threads) ----
  if (tid < 256){
    const int cc = 2*tid;
    float v0 = awe_r[0][cc]   + awe_r[1][cc]   + awe_r[2][cc]   + awe_r[3][cc];
    float v1 = awe_r[0][cc+1] + awe_r[1][cc+1] + awe_r[2][cc+1] + awe_r[3][cc+1];
    u16* zb = p.z_bf + (size_t)b*1280;
    float2 g2 = *(const float2*)&p.gatev[b*512 + cc];
    zb[256 + cc]     = f2bf(g2.x * v0);
    zb[256 + cc + 1] = f2bf(g2.y * v1);
    int tok = p.caps_s[b*256 + p.t];
    zb[tid] = p.emb_bf[tok*256 + tid];
    *(u32*)&zb[768 + cc] = *(const u32*)&p.h_bf[b*512 + cc];
  }
}

extern "C" void kernel_launch(void* const* d_in, const int* in_sizes, int n_in,
                              void* d_out, int out_size, void* d_ws, size_t ws_size,
                              hipStream_t stream){
  (void)in_sizes; (void)n_in; (void)out_size; (void)ws_size;
  const float* enc   = (const float*)d_in[0];
  const int*   caps  = (const int*)d_in[1];
  const int*   clens = (const int*)d_in[2];
  const float* Wenc  = (const float*)d_in[3];
  const float* benc  = (const float*)d_in[4];
  const float* Wdec  = (const float*)d_in[5];
  const float* bdec  = (const float*)d_in[6];
  const float* Wfull = (const float*)d_in[7];
  const float* bfull = (const float*)d_in[8];
  const float* emb   = (const float*)d_in[9];
  const float* Wfc   = (const float*)d_in[10];
  const float* bfc   = (const float*)d_in[11];
  const float* Wih   = (const float*)d_in[12];
  const float* bih   = (const float*)d_in[13];
  const float* Whh   = (const float*)d_in[14];
  const float* bhh   = (const float*)d_in[15];
  const float* Winh  = (const float*)d_in[16];
  const float* binh  = (const float*)d_in[17];
  const float* Winc  = (const float*)d_in[18];
  const float* binc  = (const float*)d_in[19];
  const float* Wfb   = (const float*)d_in[20];
  const float* bfb   = (const float*)d_in[21];

  float* out       = (float*)d_out;
  float* out_preds = out;                  // 256*255*193
  float* out_caps  = out + 12599040;       // 256*256
  float* out_dl    = out + 12664576;       // 256
  float* out_alph  = out + 12664832;       // 256*255*196
  float* out_si    = out + 25459712;       // 256

  char* w = (char*)d_ws;
  size_t off = 0;
  auto alloc = [&](size_t bytes) -> void* {
    void* pp = w + off; off += (bytes + 255) & ~(size_t)255; return pp;
  };
  int*   si      = (int*)  alloc(256*4);
  int*   dlw     = (int*)  alloc(256*4);
  int*   caps_s  = (int*)  alloc(65536*4);
  float* c       = (float*)alloc(131072*4);
  float* dec_att = (float*)alloc(65536*4);
  float* gatev   = (float*)alloc(131072*4);
  float* bc0     = (float*)alloc(1024*4);
  float* bc1     = (float*)alloc(1024*4);
  float* bc3     = (float*)alloc(2048*4);
  u16*   mean_bf = (u16*)  alloc(131072*2);
  u16*   h_bf    = (u16*)  alloc(131072*2);
  u16*   z_bf    = (u16*)  alloc(327680*2);
  u16*   Wc0     = (u16*)  alloc(524288*2);
  u16*   Wc1     = (u16*)  alloc(524288*2);
  u16*   Wc3     = (u16*)  alloc(2621440*2);
  u16*   Wenc_bf = (u16*)  alloc(131072*2);
  u16*   emb_bf  = (u16*)  alloc(49408*2);
  u16*   enc_sb  = (u16*)  alloc(25690112ull*2);   // 256 x 196 x 512 bf16
  u16*   enc_att = (u16*)  alloc(12845056ull*2);   // 50176 x 256 bf16

  k_zero<<<1024, 256, 0, stream>>>(out_preds, 12599040/4, out_alph, 12794880/4);
  k_sort<<<1, 256, 0, stream>>>(clens, si, dlw, out_dl, out_si);
  k_caps<<<256, 256, 0, stream>>>(caps, si, caps_s, out_caps);
  k_prep<<<256, 256, 0, stream>>>(enc, si, enc_sb);
  k_mean<<<256, 256, 0, stream>>>(enc, si, mean_bf);
  ConcatP cp{Wdec,bdec,Wfb,bfb,Wfc,bfc,Wih,bih,Whh,bhh,Winh,binh,Winc,binc,Wenc,emb,
             Wc0,Wc1,Wc3,Wenc_bf,emb_bf,bc0,bc1,bc3};
  k_concat<<<2048, 256, 0, stream>>>(cp);

  { // h0 / c0 : M=256, N=1024, K=512
    MfmaP g{};
    g.A = mean_bf; g.Bw = Wc0; g.bias = bc0; g.K = 512; g.N = 1024;
    g.h_bf = h_bf; g.c = c;
    k_mfma<1,1><<<dim3(16,4), 256, 0, stream>>>(g);
  }
  { // enc_att : M=50176, N=256, K=512, bf16 out
    MfmaP g{};
    g.A = enc_sb; g.Bw = Wenc_bf; g.bias = benc; g.K = 512; g.N = 256;
    g.out_bf = enc_att;
    k_mfma<0,2><<<dim3(2,784), 256, 0, stream>>>(g);
  }

  for (int t = 0; t <= 255; ++t){
    { // K1: dec_att + gate + preds(t-1) : M=256, N=1024(pad of 961), K=512
      MfmaP g{};
      g.A = h_bf; g.Bw = Wc1; g.bias = bc1; g.K = 512; g.N = 1024;
      g.dec_att = dec_att; g.gatev = gatev; g.preds = out_preds; g.dl = dlw; g.t = t;
      k_mfma<2,1><<<dim3(16,4), 256, 0, stream>>>(g);
    }
    if (t == 255) break;
    { // K2: attention + z build
      AttnP ap{enc_att, enc_sb, dec_att, gatev, Wfull, bfull, emb_bf, caps_s,
               h_bf, z_bf, out_alph, dlw, t};
      k_attn<<<256, 1024, 0, stream>>>(ap);
    }
    { // K3: gates GEMM + fused LSTM : M=256, N=2048, K=1280
      MfmaP g{};
      g.A = z_bf; g.Bw = Wc3; g.bias = bc3; g.K = 1280; g.N = 2048;
      g.dl = dlw; g.t = t; g.h_bf = h_bf; g.c = c;
      k_mfma<3,1><<<dim3(32,4), 256, 0, stream>>>(g);
    }
  }
}

// Round 2
// 7049.380 us; speedup vs baseline: 1.7013x; 1.3949x over previous
//
#include <hip/hip_runtime.h>
#include <cstdint>
#include <cstddef>

// B=256, P=196, C=512, D=512, A=256, E=256, V=193, TC=256, T=255

typedef unsigned short u16;
typedef unsigned int u32;
typedef __attribute__((ext_vector_type(8))) short short8;
typedef __attribute__((ext_vector_type(4))) float f32x4;

__device__ __forceinline__ float sigf(float x){ return 1.f/(1.f+expf(-x)); }
__device__ __forceinline__ u16 f2bf(float f){
  u32 u = __builtin_bit_cast(u32, f);
  u32 r = (u + 0x7fffu + ((u>>16)&1u)) >> 16;
  return (u16)r;
}
__device__ __forceinline__ float bf2f(u16 u){
  u32 x = ((u32)u) << 16;
  return __builtin_bit_cast(float, x);
}

// direct global->LDS DMA, 16B per lane. LDS dest is wave-uniform base + lane*16.
__device__ __forceinline__ void gload16(const void* g, void* l){
  __builtin_amdgcn_global_load_lds(
      (__attribute__((address_space(1))) void*)(g),
      (__attribute__((address_space(3))) void*)(l), 16, 0, 0);
}

__device__ __forceinline__ void wait_vm(int ahead){
  switch(ahead){
    case 6: asm volatile("s_waitcnt vmcnt(12)" ::: "memory"); break;
    case 5: asm volatile("s_waitcnt vmcnt(10)" ::: "memory"); break;
    case 4: asm volatile("s_waitcnt vmcnt(8)"  ::: "memory"); break;
    case 3: asm volatile("s_waitcnt vmcnt(6)"  ::: "memory"); break;
    case 2: asm volatile("s_waitcnt vmcnt(4)"  ::: "memory"); break;
    case 1: asm volatile("s_waitcnt vmcnt(2)"  ::: "memory"); break;
    default: asm volatile("s_waitcnt vmcnt(0)" ::: "memory"); break;
  }
}

// ---------------- zero preds/alphas (harness poisons d_out every launch) ----------------
__global__ void k_zero(float* a, int na4, float* b, int nb4){
  int i = blockIdx.x*blockDim.x + threadIdx.x;
  int stride = gridDim.x*blockDim.x;
  float4 z = make_float4(0.f,0.f,0.f,0.f);
  for (int j = i; j < na4; j += stride) ((float4*)a)[j] = z;
  for (int j = i; j < nb4; j += stride) ((float4*)b)[j] = z;
}

// ---------------- sort (stable descending by length) ----------------
__global__ void k_sort(const int* cap_lens, int* si, int* dlw, float* out_dl, float* out_si){
  __shared__ int lens[256];
  int tid = threadIdx.x;
  lens[tid] = cap_lens[tid];
  __syncthreads();
  int L = lens[tid];
  int rank = 0;
  for (int j = 0; j < 256; ++j){
    int Lj = lens[j];
    rank += ((Lj > L) || (Lj == L && j < tid)) ? 1 : 0;
  }
  si[rank] = tid;
  dlw[rank] = L - 1;
  out_dl[rank] = (float)(L - 1);
  out_si[rank] = (float)tid;
}

// ---------------- caps gather ----------------
__global__ void k_caps(const int* caps, const int* si, int* caps_s, float* out_caps){
  int b = blockIdx.x, t = threadIdx.x;
  int v = caps[si[b]*256 + t];
  caps_s[b*256 + t] = v;
  out_caps[b*256 + t] = (float)v;
}

// ---------------- gather+convert encoder rows to bf16 (sorted order) ----------------
__global__ void k_prep(const float* enc, const int* si, u16* enc_sb){
  int b = blockIdx.x, tid = threadIdx.x;
  const float* src = enc + (size_t)si[b]*100352;   // 196*512
  u16* dst = enc_sb + (size_t)b*100352;
  for (int i = tid; i < 25088; i += 256){
    float4 v = *(const float4*)&src[i*4];
    ushort4 o;
    o.x = f2bf(v.x); o.y = f2bf(v.y); o.z = f2bf(v.z); o.w = f2bf(v.w);
    *(ushort4*)&dst[i*4] = o;
  }
}

// ---------------- mean of encoder rows (sorted order), bf16 out ----------------
__global__ void k_mean(const float* enc, const int* si, u16* mean_bf){
  int b = blockIdx.x, tid = threadIdx.x;
  const float* eb = enc + (size_t)si[b]*100352;
  int cc = 2*tid;
  float s0 = 0.f, s1 = 0.f;
  #pragma unroll 4
  for (int pp = 0; pp < 196; ++pp){
    float2 v = *(const float2*)&eb[(size_t)pp*512 + cc];
    s0 += v.x; s1 += v.y;
  }
  mean_bf[b*512 + cc]     = f2bf(s0 * (1.f/196.f));
  mean_bf[b*512 + cc + 1] = f2bf(s1 * (1.f/196.f));
}

// ---------------- weight concat + bf16 convert ----------------
struct ConcatP {
  const float *Wdec,*bdec,*Wfb,*bfb,*Wfc,*bfc,*Wih,*bih,*Whh,*bhh,*Winh,*binh,*Winc,*binc,*Wenc,*emb;
  u16 *Wc0,*Wc1,*Wc3,*Wenc_bf,*emb_bf;
  float *bc0,*bc1,*bc3;
};
__global__ void k_concat(ConcatP p){
  int idx = blockIdx.x*blockDim.x + threadIdx.x;
  int stride = gridDim.x*blockDim.x;
  for (int i = idx; i < 1024*512; i += stride){
    int n = i >> 9, k = i & 511;
    float v = (n < 512) ? p.Winh[n*512 + k] : p.Winc[(n-512)*512 + k];
    p.Wc0[i] = f2bf(v);
  }
  for (int i = idx; i < 1024; i += stride)
    p.bc0[i] = (i < 512) ? p.binh[i] : p.binc[i-512];
  for (int i = idx; i < 1024*512; i += stride){
    int n = i >> 9, k = i & 511;
    float v = (n < 256) ? p.Wdec[n*512+k]
            : (n < 768) ? p.Wfb[(n-256)*512+k]
            : (n < 961) ? p.Wfc[(n-768)*512+k] : 0.f;
    p.Wc1[i] = f2bf(v);
  }
  for (int i = idx; i < 1024; i += stride)
    p.bc1[i] = (i < 256) ? p.bdec[i] : (i < 768) ? p.bfb[i-256] : (i < 961) ? p.bfc[i-768] : 0.f;
  // Wc3: gate-interleaved [W_ih | W_hh] (2048 x 1280), row n'=4*j+g -> orig row g*512+j
  for (int i = idx; i < 2048*1280; i += stride){
    int n = i / 1280, k = i - n*1280;
    int j = n >> 2, g = n & 3, orow = g*512 + j;
    float v = (k < 768) ? p.Wih[orow*768 + k] : p.Whh[orow*512 + (k - 768)];
    p.Wc3[i] = f2bf(v);
  }
  for (int i = idx; i < 2048; i += stride){
    int j = i >> 2, g = i & 3, orow = g*512 + j;
    p.bc3[i] = p.bih[orow] + p.bhh[orow];
  }
  for (int i = idx; i < 256*512; i += stride) p.Wenc_bf[i] = f2bf(p.Wenc[i]);
  for (int i = idx; i < 193*256; i += stride) p.emb_bf[i] = f2bf(p.emb[i]);
}

// ---------------- bf16 MFMA GEMM (register-staged, 4 waves) — prologue only ----------------
// MODE 0: enc_att -> bf16 (+bias);  MODE 1: init h/c
struct MfmaP {
  const u16* A; const u16* Bw; const float* bias;
  int K, N;
  u16* out_bf;
  u16* h_bf; float* c;
  float* dec_att; float* gatev; float* preds; const int* dl; int t;
};

template<int MODE, int NT>
__global__ __launch_bounds__(256) void k_mfma(MfmaP p){
  __shared__ __align__(16) unsigned char smem[16384 + 16384*NT];
  u16* As0 = (u16*)smem;                 // [2][64*64]
  u16* Bs0 = (u16*)(smem + 16384);       // [2][64*64*NT]

  const int tid  = threadIdx.x;
  const int bn0  = blockIdx.x * 64 * NT;
  const int bm0  = blockIdx.y * 64;
  const int wave = tid >> 6;
  const int lane = tid & 63;
  const int ln   = lane & 15;
  const int quad = lane >> 4;

  f32x4 acc[4][NT] = {};
  short8 pa[2], pb[2*NT];

  const int srow = tid >> 3;          // 0..31
  const int sgc  = tid & 7;           // granule col 0..7

  // prefetch k0=0
  #pragma unroll
  for (int r = 0; r < 2; ++r)
    pa[r] = *(const short8*)(p.A + (size_t)(bm0 + srow + 32*r)*p.K + sgc*8);
  #pragma unroll
  for (int r = 0; r < 2*NT; ++r)
    pb[r] = *(const short8*)(p.Bw + (size_t)(bn0 + srow + 32*r)*p.K + sgc*8);
  // store buf 0
  #pragma unroll
  for (int r = 0; r < 2; ++r){
    int row = srow + 32*r;
    *(short8*)&As0[row*64 + ((sgc ^ (row & 7))<<3)] = pa[r];
  }
  #pragma unroll
  for (int r = 0; r < 2*NT; ++r){
    int row = srow + 32*r;
    *(short8*)&Bs0[row*64 + ((sgc ^ (row & 7))<<3)] = pb[r];
  }

  const int nIter = p.K >> 6;
  int ib = 0;
  for (int it = 0; ; ){
    __syncthreads();
    const bool more = (it + 1 < nIter);
    if (more){
      int k0 = (it + 1) << 6;
      #pragma unroll
      for (int r = 0; r < 2; ++r)
        pa[r] = *(const short8*)(p.A + (size_t)(bm0 + srow + 32*r)*p.K + k0 + sgc*8);
      #pragma unroll
      for (int r = 0; r < 2*NT; ++r)
        pb[r] = *(const short8*)(p.Bw + (size_t)(bn0 + srow + 32*r)*p.K + k0 + sgc*8);
    }
    const u16* As = &As0[ib*4096];
    const u16* Bs = &Bs0[ib*4096*NT];
    #pragma unroll
    for (int kk = 0; kk < 2; ++kk){
      short8 af[4], bfr[NT];
      #pragma unroll
      for (int mt = 0; mt < 4; ++mt){
        int row = mt*16 + ln;
        int g = kk*4 + quad;
        af[mt] = *(const short8*)&As[row*64 + ((g ^ (row & 7))<<3)];
      }
      #pragma unroll
      for (int nt = 0; nt < NT; ++nt){
        int row = (wave*NT + nt)*16 + ln;
        int g = kk*4 + quad;
        bfr[nt] = *(const short8*)&Bs[row*64 + ((g ^ (row & 7))<<3)];
      }
      #pragma unroll
      for (int mt = 0; mt < 4; ++mt)
        #pragma unroll
        for (int nt = 0; nt < NT; ++nt)
          acc[mt][nt] = __builtin_amdgcn_mfma_f32_16x16x32_bf16(af[mt], bfr[nt], acc[mt][nt], 0, 0, 0);
    }
    if (!more) break;
    ib ^= 1;
    u16* Aw = &As0[ib*4096];
    u16* Bww = &Bs0[ib*4096*NT];
    #pragma unroll
    for (int r = 0; r < 2; ++r){
      int row = srow + 32*r;
      *(short8*)&Aw[row*64 + ((sgc ^ (row & 7))<<3)] = pa[r];
    }
    #pragma unroll
    for (int r = 0; r < 2*NT; ++r){
      int row = srow + 32*r;
      *(short8*)&Bww[row*64 + ((sgc ^ (row & 7))<<3)] = pb[r];
    }
    ++it;
  }

  #pragma unroll
  for (int nt = 0; nt < NT; ++nt){
    int n = bn0 + (wave*NT + nt)*16 + ln;
    float bv = p.bias[n];
    #pragma unroll
    for (int mt = 0; mt < 4; ++mt)
      #pragma unroll
      for (int r = 0; r < 4; ++r){
        int m = bm0 + mt*16 + quad*4 + r;
        float v = acc[mt][nt][r] + bv;
        if (MODE == 0){
          p.out_bf[(size_t)m*p.N + n] = f2bf(v);
        } else { // MODE 1
          if (n < 512) p.h_bf[m*512 + n] = f2bf(v);
          else         p.c[m*512 + n - 512] = v;
        }
      }
  }
}

// ---------------- ring-pipelined GEMM for the t-loop (global_load_lds, 8 waves) ----------------
// C(MxN) = A(MxK)*B(NxK)^T, tile 64x64, BK=64 chunks, 8-slot LDS ring, prefetch depth 6.
// MODE 2: K1 (dec_att + gate + preds);  MODE 3: K3 fused LSTM.
#define RING_COMPUTE(ci_) do { \
  const u16* As = (const u16*)(smem + ((ci_)&7)*16384); \
  const u16* Bs = (const u16*)(smem + ((ci_)&7)*16384 + 8192); \
  for (int kk = 0; kk < 2; ++kk){ \
    short8 af0, af1, bfv; \
    { int row = mh*32 + ln;      int g = kk*4 + quad; af0 = *(const short8*)&As[row*64 + ((g ^ (row&7))<<3)]; } \
    { int row = mh*32 + 16 + ln; int g = kk*4 + quad; af1 = *(const short8*)&As[row*64 + ((g ^ (row&7))<<3)]; } \
    { int row = nq*16 + ln;      int g = kk*4 + quad; bfv = *(const short8*)&Bs[row*64 + ((g ^ (row&7))<<3)]; } \
    acc0 = __builtin_amdgcn_mfma_f32_16x16x32_bf16(af0, bfv, acc0, 0, 0, 0); \
    acc1 = __builtin_amdgcn_mfma_f32_16x16x32_bf16(af1, bfv, acc1, 0, 0, 0); \
  } \
} while(0)

template<int MODE, int NC>
__global__ __launch_bounds__(512, 2) void k_gemm_ring(MfmaP p){
  __shared__ __align__(16) unsigned char smem[131072];   // 8 slots x (A 8KB + B 8KB)
  const int tid = threadIdx.x;
  const int bn0 = blockIdx.x * 64, bm0 = blockIdx.y * 64;
  if (MODE == 2){ if (p.dl[bm0] <  p.t) return; }
  if (MODE == 3){ if (p.dl[bm0] <= p.t) return; }
  constexpr int K = NC * 64;
  const int w = tid >> 6, l = tid & 63;
  const int r_loc = (w<<3) + (l>>3);                   // 0..63 (row within tile)
  const int gcol  = (((l & 7) ^ (r_loc & 7)) << 3);    // pre-swizzled source granule
  const u16* gA = p.A  + (size_t)(bm0 + r_loc)*K + gcol;
  const u16* gB = p.Bw + (size_t)(bn0 + r_loc)*K + gcol;
  unsigned char* ldsA = smem + w*1024;                 // + slot*16384
  unsigned char* ldsB = smem + 8192 + w*1024;
  const int mh = w >> 2, nq = w & 3;
  const int ln = l & 15, quad = l >> 4;
  f32x4 acc0 = {0.f,0.f,0.f,0.f}, acc1 = {0.f,0.f,0.f,0.f};

  constexpr int D = 6;
  #pragma unroll
  for (int ci = 0; ci < D; ++ci){
    gload16(gA + ci*64, ldsA + (ci&7)*16384);
    gload16(gB + ci*64, ldsB + (ci&7)*16384);
  }
  int ci = 0;
  for (; ci < NC - D; ++ci){
    gload16(gA + (ci+D)*64, ldsA + ((ci+D)&7)*16384);
    gload16(gB + (ci+D)*64, ldsB + ((ci+D)&7)*16384);
    asm volatile("s_waitcnt vmcnt(12)" ::: "memory");
    __builtin_amdgcn_s_barrier();
    __builtin_amdgcn_sched_barrier(0);
    RING_COMPUTE(ci);
  }
  #pragma unroll
  for (; ci < NC; ++ci){
    wait_vm(NC - 1 - ci);
    __builtin_amdgcn_s_barrier();
    __builtin_amdgcn_sched_barrier(0);
    RING_COMPUTE(ci);
  }

  if (MODE == 2){
    const int n_loc = nq*16 + ln;
    const int n = bn0 + n_loc;
    const float bv = p.bias[n];
    #pragma unroll
    for (int mt = 0; mt < 2; ++mt){
      f32x4 a = mt ? acc1 : acc0;
      #pragma unroll
      for (int r = 0; r < 4; ++r){
        int m = bm0 + mh*32 + mt*16 + quad*4 + r;
        float v = a[r] + bv;
        if (n < 256)      p.dec_att[m*256 + n] = v;
        else if (n < 768) p.gatev[m*512 + n - 256] = sigf(v);
        else if (n < 961){
          int tp = p.t - 1;
          if (tp >= 0)
            p.preds[((size_t)m*255 + tp)*193 + (n - 768)] = (tp < p.dl[m]) ? v : 0.f;
        }
      }
    }
  } else {
    // MODE 3: gates tile -> LDS (+bias), regroup (i,f,g,o) quads, fused LSTM pointwise
    float* Cs = (float*)smem;            // 64 x 68 f32 overlay
    const int n_loc = nq*16 + ln;
    const float bv = p.bias[bn0 + n_loc];
    __syncthreads();
    #pragma unroll
    for (int mt = 0; mt < 2; ++mt){
      f32x4 a = mt ? acc1 : acc0;
      #pragma unroll
      for (int r = 0; r < 4; ++r)
        Cs[(mh*32 + mt*16 + quad*4 + r)*68 + n_loc] = a[r] + bv;
    }
    __syncthreads();
    #pragma unroll
    for (int rr = 0; rr < 2; ++rr){
      int idx = rr*512 + tid;            // 64 rows x 16 unit-quads
      int m = idx >> 4, jl = idx & 15;
      float4 g4 = *(const float4*)&Cs[m*68 + jl*4];
      int gm = bm0 + m;
      int gj = (bn0 >> 2) + jl;
      if (p.t < p.dl[gm]){
        float ig = sigf(g4.x), fg = sigf(g4.y);
        float gg = tanhf(g4.z), og = sigf(g4.w);
        float cn = fg * p.c[gm*512 + gj] + ig * gg;
        float hn = og * tanhf(cn);
        p.c[gm*512 + gj] = cn;
        p.h_bf[gm*512 + gj] = f2bf(hn);
      }
    }
  }
}

// ---------------- attention per batch element (bf16 streams) ----------------
// 1024 threads (16 waves): scores split 4-way over A-dim, awe split 4-way over P.
struct AttnP {
  const u16* enc_att_bf; const u16* enc_sb;
  const float* dec_att; const float* gatev;
  const float* wfull; const float* bfull;
  const u16* emb_bf; const int* caps_s;
  const u16* h_bf; u16* z_bf; float* alphas; const int* dl; int t;
};
__global__ __launch_bounds__(1024) void k_attn(AttnP p){
  __shared__ __align__(16) float da[256];
  __shared__ __align__(16) float wfs[256];
  __shared__ __align__(16) float sc[256];       // scores -> alpha
  __shared__ __align__(16) float awe_r[4][512]; // per-quarter awe partials
  __shared__ float red[20];                     // [0..15] wave partials, [16] combined
  const int b = blockIdx.x, tid = threadIdx.x;
  if (p.t >= p.dl[b]) return;      // inactive: alphas pre-zeroed, h/c/z untouched
  if (tid < 256){
    da[tid]  = p.dec_att[b*256 + tid];
    wfs[tid] = p.wfull[tid];
  }
  __syncthreads();

  // ---- scores: thread (pr, aq) computes partial over 64 A-entries ----
  {
    const int pr = tid >> 2, aq = tid & 3;
    float s = 0.f;
    if (pr < 196){
      const u16* row = p.enc_att_bf + ((size_t)b*196 + pr)*256 + aq*64;
      const float* dd = &da[aq*64];
      const float* ww = &wfs[aq*64];
      #pragma unroll
      for (int i = 0; i < 8; ++i){
        short8 v = *(const short8*)(row + i*8);
        #pragma unroll
        for (int j = 0; j < 8; ++j)
          s += fmaxf(bf2f((u16)v[j]) + dd[i*8+j], 0.f) * ww[i*8+j];
      }
    }
    // quad reduce (lanes 4p..4p+3 share pr)
    s += __shfl_xor(s, 1, 64);
    s += __shfl_xor(s, 2, 64);
    if ((tid & 3) == 0 && pr < 196) sc[pr] = s + p.bfull[0];
  }
  __syncthreads();

  // ---- softmax over 196 (all waves run the shfl; only waves 0-3 hold data) ----
  const int wid = tid >> 6, lane = tid & 63;
  float sv = (tid < 196) ? sc[tid] : -1e30f;
  float mx = sv;
  for (int o = 32; o > 0; o >>= 1) mx = fmaxf(mx, __shfl_down(mx, o, 64));
  if (lane == 0) red[wid] = mx;
  __syncthreads();
  if (tid == 0) red[16] = fmaxf(fmaxf(red[0], red[1]), fmaxf(red[2], red[3]));
  __syncthreads();
  mx = red[16];
  float e = (tid < 196) ? expf(sv - mx) : 0.f;
  float sm = e;
  for (int o = 32; o > 0; o >>= 1) sm += __shfl_down(sm, o, 64);
  if (lane == 0) red[wid] = sm;
  __syncthreads();
  if (tid == 0) red[16] = red[0] + red[1] + red[2] + red[3];
  __syncthreads();
  const float inv = 1.f / red[16];
  if (tid < 256) sc[tid] = e * inv;
  __syncthreads();
  if (tid < 196)
    p.alphas[((size_t)b*255 + p.t)*196 + tid] = sc[tid];

  // ---- awe: thread (q, cp): quarter q of P, channel pair cc ----
  {
    const int q = tid >> 8, cp = tid & 255, cc = 2*cp;
    const u16* eb = p.enc_sb + (size_t)b*100352;
    const int p0 = q*49;
    float v0 = 0.f, v1 = 0.f;
    #pragma unroll 7
    for (int i = 0; i < 49; ++i){
      int pp = p0 + i;
      u32 u = *(const u32*)&eb[(size_t)pp*512 + cc];
      float a = sc[pp];
      v0 += a * bf2f((u16)(u & 0xffffu));
      v1 += a * bf2f((u16)(u >> 16));
    }
    *(float2*)&awe_r[q][cc] = make_float2(v0, v1);
  }
  __syncthreads();

  // ---- combine + z assembly (first 256 threads) ----
  if (tid < 256){
    const int cc = 2*tid;
    float v0 = awe_r[0][cc]   + awe_r[1][cc]   + awe_r[2][cc]   + awe_r[3][cc];
    float v1 = awe_r[0][cc+1] + awe_r[1][cc+1] + awe_r[2][cc+1] + awe_r[3][cc+1];
    u16* zb = p.z_bf + (size_t)b*1280;
    float2 g2 = *(const float2*)&p.gatev[b*512 + cc];
    zb[256 + cc]     = f2bf(g2.x * v0);
    zb[256 + cc + 1] = f2bf(g2.y * v1);
    int tok = p.caps_s[b*256 + p.t];
    zb[tid] = p.emb_bf[tok*256 + tid];
    *(u32*)&zb[768 + cc] = *(const u32*)&p.h_bf[b*512 + cc];
  }
}

extern "C" void kernel_launch(void* const* d_in, const int* in_sizes, int n_in,
                              void* d_out, int out_size, void* d_ws, size_t ws_size,
                              hipStream_t stream){
  (void)in_sizes; (void)n_in; (void)out_size; (void)ws_size;
  const float* enc   = (const float*)d_in[0];
  const int*   caps  = (const int*)d_in[1];
  const int*   clens = (const int*)d_in[2];
  const float* Wenc  = (const float*)d_in[3];
  const float* benc  = (const float*)d_in[4];
  const float* Wdec  = (const float*)d_in[5];
  const float* bdec  = (const float*)d_in[6];
  const float* Wfull = (const float*)d_in[7];
  const float* bfull = (const float*)d_in[8];
  const float* emb   = (const float*)d_in[9];
  const float* Wfc   = (const float*)d_in[10];
  const float* bfc   = (const float*)d_in[11];
  const float* Wih   = (const float*)d_in[12];
  const float* bih   = (const float*)d_in[13];
  const float* Whh   = (const float*)d_in[14];
  const float* bhh   = (const float*)d_in[15];
  const float* Winh  = (const float*)d_in[16];
  const float* binh  = (const float*)d_in[17];
  const float* Winc  = (const float*)d_in[18];
  const float* binc  = (const float*)d_in[19];
  const float* Wfb   = (const float*)d_in[20];
  const float* bfb   = (const float*)d_in[21];

  float* out       = (float*)d_out;
  float* out_preds = out;                  // 256*255*193
  float* out_caps  = out + 12599040;       // 256*256
  float* out_dl    = out + 12664576;       // 256
  float* out_alph  = out + 12664832;       // 256*255*196
  float* out_si    = out + 25459712;       // 256

  char* w = (char*)d_ws;
  size_t off = 0;
  auto alloc = [&](size_t bytes) -> void* {
    void* pp = w + off; off += (bytes + 255) & ~(size_t)255; return pp;
  };
  int*   si      = (int*)  alloc(256*4);
  int*   dlw     = (int*)  alloc(256*4);
  int*   caps_s  = (int*)  alloc(65536*4);
  float* c       = (float*)alloc(131072*4);
  float* dec_att = (float*)alloc(65536*4);
  float* gatev   = (float*)alloc(131072*4);
  float* bc0     = (float*)alloc(1024*4);
  float* bc1     = (float*)alloc(1024*4);
  float* bc3     = (float*)alloc(2048*4);
  u16*   mean_bf = (u16*)  alloc(131072*2);
  u16*   h_bf    = (u16*)  alloc(131072*2);
  u16*   z_bf    = (u16*)  alloc(327680*2);
  u16*   Wc0     = (u16*)  alloc(524288*2);
  u16*   Wc1     = (u16*)  alloc(524288*2);
  u16*   Wc3     = (u16*)  alloc(2621440*2);
  u16*   Wenc_bf = (u16*)  alloc(131072*2);
  u16*   emb_bf  = (u16*)  alloc(49408*2);
  u16*   enc_sb  = (u16*)  alloc(25690112ull*2);   // 256 x 196 x 512 bf16
  u16*   enc_att = (u16*)  alloc(12845056ull*2);   // 50176 x 256 bf16

  k_zero<<<1024, 256, 0, stream>>>(out_preds, 12599040/4, out_alph, 12794880/4);
  k_sort<<<1, 256, 0, stream>>>(clens, si, dlw, out_dl, out_si);
  k_caps<<<256, 256, 0, stream>>>(caps, si, caps_s, out_caps);
  k_prep<<<256, 256, 0, stream>>>(enc, si, enc_sb);
  k_mean<<<256, 256, 0, stream>>>(enc, si, mean_bf);
  ConcatP cp{Wdec,bdec,Wfb,bfb,Wfc,bfc,Wih,bih,Whh,bhh,Winh,binh,Winc,binc,Wenc,emb,
             Wc0,Wc1,Wc3,Wenc_bf,emb_bf,bc0,bc1,bc3};
  k_concat<<<2048, 256, 0, stream>>>(cp);

  { // h0 / c0 : M=256, N=1024, K=512
    MfmaP g{};
    g.A = mean_bf; g.Bw = Wc0; g.bias = bc0; g.K = 512; g.N = 1024;
    g.h_bf = h_bf; g.c = c;
    k_mfma<1,1><<<dim3(16,4), 256, 0, stream>>>(g);
  }
  { // enc_att : M=50176, N=256, K=512, bf16 out
    MfmaP g{};
    g.A = enc_sb; g.Bw = Wenc_bf; g.bias = benc; g.K = 512; g.N = 256;
    g.out_bf = enc_att;
    k_mfma<0,2><<<dim3(2,784), 256, 0, stream>>>(g);
  }

  for (int t = 0; t <= 255; ++t){
    { // K1: dec_att + gate + preds(t-1) : M=256, N=1024(pad of 961), K=512
      MfmaP g{};
      g.A = h_bf; g.Bw = Wc1; g.bias = bc1; g.K = 512; g.N = 1024;
      g.dec_att = dec_att; g.gatev = gatev; g.preds = out_preds; g.dl = dlw; g.t = t;
      k_gemm_ring<2,8><<<dim3(16,4), 512, 0, stream>>>(g);
    }
    if (t == 255) break;
    { // K2: attention + z build
      AttnP ap{enc_att, enc_sb, dec_att, gatev, Wfull, bfull, emb_bf, caps_s,
               h_bf, z_bf, out_alph, dlw, t};
      k_attn<<<256, 1024, 0, stream>>>(ap);
    }
    { // K3: gates GEMM + fused LSTM : M=256, N=2048, K=1280
      MfmaP g{};
      g.A = z_bf; g.Bw = Wc3; g.bias = bc3; g.K = 1280; g.N = 2048;
      g.dl = dlw; g.t = t; g.h_bf = h_bf; g.c = c;
      k_gemm_ring<3,20><<<dim3(32,4), 512, 0, stream>>>(g);
    }
  }
}